// Round 4
// baseline (127.260 us; speedup 1.0000x reference)
//
#include <hip/hip_runtime.h>
#include <float.h>

#define N_ROWS   131072
#define DIM      64
#define NCODES   1024
#define MB       64      // rows per block
#define NCHUNK   16      // 64 codes per chunk

typedef __attribute__((ext_vector_type(8))) short short8;
typedef __attribute__((ext_vector_type(4))) float floatx4;

// ws layout (bytes):
// [0,     4096)   nh     f32[1024]   -0.5*||e_k||^2
// [4096,  8192)   counts i32[1024]
// [8192, 16384)   ssePart f32[2048]
// [16384, 278528) blob: per (chunk c, wave w, lane l) 64B =
//                 {ehi ks0, ehi ks1, elo ks0, elo ks1} 16B fragments

__device__ inline ushort f2bf(float f) {
    uint u = __float_as_uint(f);
    return (ushort)((u + 0x7FFFu + ((u >> 16) & 1u)) >> 16);   // RTNE
}
__device__ inline float bf2f(ushort s) { return __uint_as_float(((uint)s) << 16); }

// XOR swizzle within a 128B row (T2/G4): kills 16-lane same-column bank conflicts
__device__ inline uint swz(uint row, uint b) { return row * 128u + (b ^ ((row & 7u) << 4)); }

__global__ void vq_prep(const float* __restrict__ emb, float* __restrict__ nh,
                        int* __restrict__ counts, ushort* __restrict__ blob) {
    int g = blockIdx.x * 256 + threadIdx.x;     // 0..4095 == (c*4+w)*64+l
    int l = g & 63;
    int l15 = l & 15, lhi = l >> 4;
    int c = g >> 8, w = (g >> 6) & 3;
    int code = c * 64 + w * 16 + l15;
    int k0 = lhi * 8;
    const float* er = emb + (size_t)code * DIM;

    ushort tmp[32];
    #pragma unroll
    for (int j = 0; j < 8; ++j) {
        float a = er[k0 + j], b = er[32 + k0 + j];
        ushort ha = f2bf(a), hb = f2bf(b);
        tmp[j]      = ha;
        tmp[8 + j]  = hb;
        tmp[16 + j] = f2bf(a - bf2f(ha));
        tmp[24 + j] = f2bf(b - bf2f(hb));
    }
    ushort* dst = blob + (size_t)g * 32;        // 64 bytes
    #pragma unroll
    for (int i = 0; i < 4; ++i)
        *(short8*)(dst + i * 8) = *(const short8*)(tmp + i * 8);

    if (g < NCODES) {
        float s = 0.f;
        const float* e = emb + (size_t)g * DIM;
        #pragma unroll
        for (int d = 0; d < DIM; ++d) s += e[d] * e[d];
        nh[g] = -0.5f * s;
        counts[g] = 0;
    }
}

__global__ __launch_bounds__(256, 3) void vq_main(
        const float* __restrict__ x, const float* __restrict__ emb,
        const ushort* __restrict__ blob, const float* __restrict__ nh,
        float* __restrict__ out, int* __restrict__ counts, float* __restrict__ ssePart) {

    __shared__ __align__(16) ushort xh[MB * DIM];    // 8KB, swizzled bf16-hi of x
    __shared__ __align__(16) float  xf[MB][DIM];     // 16KB, exact f32 x
    __shared__ float2 part[MB][4];
    __shared__ int    rowIdx[MB];
    __shared__ float  wred[4];

    const int tid = threadIdx.x;
    const int lane = tid & 63;
    const int w = tid >> 6;             // wave 0..3: codes [w*16, w*16+16) of each chunk
    const int cB = w * 16;
    const int l15 = lane & 15, lhi = lane >> 4;
    const int rowBase = blockIdx.x * MB;

    // ---- stage x: f32 copy + bf16-hi (swizzled), once per block ----
    #pragma unroll
    for (int i = 0; i < 4; ++i) {
        int f = tid + 256 * i; int r = f >> 4, d4 = f & 15;
        float4 v = ((const float4*)x)[(size_t)(rowBase + r) * 16 + d4];
        *(float4*)&xf[r][d4 * 4] = v;
        ushort4 h = make_ushort4(f2bf(v.x), f2bf(v.y), f2bf(v.z), f2bf(v.w));
        *(ushort4*)((char*)xh + swz((uint)r, (uint)d4 * 8u)) = h;
    }
    __syncthreads();

    // ---- A fragments (x-hi) register-resident ----
    short8 afr[4][2];
    #pragma unroll
    for (int rm = 0; rm < 4; ++rm)
        #pragma unroll
        for (int ks = 0; ks < 2; ++ks)
            afr[rm][ks] = *(const short8*)((char*)xh + swz((uint)(rm * 16 + l15),
                                                           (uint)(ks * 64 + lhi * 16)));

    float b1[16];
    int   i1[16];
    #pragma unroll
    for (int s = 0; s < 16; ++s) { b1[s] = -FLT_MAX; i1[s] = 0; }

    const int codeBase = cB + l15;
    const ushort* bp = blob + ((size_t)w * 64 + lane) * 32;   // +8192 ushorts per chunk

    // ---- 2-deep software pipeline: cur / nxt / fut register sets ----
    short8 cur[4], nxt[4];
    float nhc, nhn;
    #pragma unroll
    for (int i = 0; i < 4; ++i) cur[i] = *(const short8*)(bp + i * 8);
    nhc = nh[codeBase];
    {
        const ushort* np_ = bp + 8192;
        #pragma unroll
        for (int i = 0; i < 4; ++i) nxt[i] = *(const short8*)(np_ + i * 8);
        nhn = nh[64 + codeBase];
    }

    #pragma unroll 4
    for (int c = 0; c < NCHUNK; ++c) {
        short8 fut[4] = {cur[0], cur[1], cur[2], cur[3]};
        float nhf = 0.f;
        if (c + 2 < NCHUNK) {
            const ushort* fp = bp + (size_t)(c + 2) * 8192;
            #pragma unroll
            for (int i = 0; i < 4; ++i) fut[i] = *(const short8*)(fp + i * 8);
            nhf = nh[(c + 2) * 64 + codeBase];
        }

        // acc init = -0.5||e||^2 ; accumulate x.e  ->  acc = dot - 0.5||e||^2 = -dist
        floatx4 acc[4];
        #pragma unroll
        for (int rm = 0; rm < 4; ++rm) acc[rm] = (floatx4){nhc, nhc, nhc, nhc};

        #pragma unroll
        for (int rm = 0; rm < 4; ++rm) {
            acc[rm] = __builtin_amdgcn_mfma_f32_16x16x32_bf16(afr[rm][0], cur[0], acc[rm], 0, 0, 0);
            acc[rm] = __builtin_amdgcn_mfma_f32_16x16x32_bf16(afr[rm][0], cur[2], acc[rm], 0, 0, 0);
            acc[rm] = __builtin_amdgcn_mfma_f32_16x16x32_bf16(afr[rm][1], cur[1], acc[rm], 0, 0, 0);
            acc[rm] = __builtin_amdgcn_mfma_f32_16x16x32_bf16(afr[rm][1], cur[3], acc[rm], 0, 0, 0);
        }

        // top-1 (max of -dist); codes ascend per lane -> strict > keeps lowest index
        const int ccode = codeBase + c * 64;
        #pragma unroll
        for (int rm = 0; rm < 4; ++rm)
            #pragma unroll
            for (int j = 0; j < 4; ++j) {
                float d = acc[rm][j];
                int s = rm * 4 + j;
                if (d > b1[s]) { b1[s] = d; i1[s] = ccode; }
            }

        #pragma unroll
        for (int i = 0; i < 4; ++i) { cur[i] = nxt[i]; nxt[i] = fut[i]; }
        nhc = nhn; nhn = nhf;
    }

    // ---- cross-lane argmax merge within each 16-lane code group ----
    #pragma unroll
    for (int s = 0; s < 16; ++s) {
        float d1 = b1[s]; int j1 = i1[s];
        #pragma unroll
        for (int m = 1; m < 16; m <<= 1) {
            float od = __shfl_xor(d1, m);
            int   oj = __shfl_xor(j1, m);
            bool t = (od > d1) || (od == d1 && oj < j1);
            d1 = t ? od : d1;
            j1 = t ? oj : j1;
        }
        if (l15 == 0)
            part[(s >> 2) * 16 + lhi * 4 + (s & 3)][w] = make_float2(d1, __int_as_float(j1));
    }
    __syncthreads();

    // ---- per-row merge of 4 wave partials ----
    if (tid < MB) {
        float2 p = part[tid][0];
        float m1 = p.x; int j1 = __float_as_int(p.y);
        #pragma unroll
        for (int g = 1; g < 4; ++g) {
            float2 q = part[tid][g];
            int k1 = __float_as_int(q.y);
            bool t = (q.x > m1) || (q.x == m1 && k1 < j1);
            m1 = t ? q.x : m1;
            j1 = t ? k1 : j1;
        }
        rowIdx[tid] = j1;
        atomicAdd(&counts[j1], 1);
    }
    __syncthreads();

    // ---- epilogue: gather, straight-through out, SSE partial ----
    float myss = 0.f;
    #pragma unroll
    for (int i = 0; i < 4; ++i) {
        int f = tid + 256 * i; int r = f >> 4, d4 = f & 15;
        int idx = rowIdx[r];
        float4 q = ((const float4*)emb)[(size_t)idx * 16 + d4];
        float4 xv = *(const float4*)&xf[r][d4 * 4];
        float4 o;
        o.x = xv.x + (q.x - xv.x);
        o.y = xv.y + (q.y - xv.y);
        o.z = xv.z + (q.z - xv.z);
        o.w = xv.w + (q.w - xv.w);
        ((float4*)out)[(size_t)(rowBase + r) * 16 + d4] = o;
        float gx = o.x - xv.x, gy = o.y - xv.y, gz = o.z - xv.z, gw = o.w - xv.w;
        myss += gx * gx + gy * gy + gz * gz + gw * gw;
    }
    #pragma unroll
    for (int m = 32; m >= 1; m >>= 1) myss += __shfl_down(myss, m);
    if (lane == 0) wred[w] = myss;
    __syncthreads();
    if (tid == 0)
        ssePart[blockIdx.x] = wred[0] + wred[1] + wred[2] + wred[3];
}

__global__ void vq_final(const int* __restrict__ counts, const float* __restrict__ ssePart,
                         float* __restrict__ out) {
    __shared__ float pe[16], ps[16];
    int k = threadIdx.x;   // 1024 threads
    float p = (float)counts[k] * (1.0f / (float)N_ROWS);
    float ent = p * logf(p + 1e-10f);
    float sp = ssePart[k] + ssePart[k + 1024];
    #pragma unroll
    for (int m = 32; m >= 1; m >>= 1) {
        ent += __shfl_down(ent, m);
        sp  += __shfl_down(sp, m);
    }
    if ((k & 63) == 0) { pe[k >> 6] = ent; ps[k >> 6] = sp; }
    __syncthreads();
    if (k == 0) {
        float es = 0.f, ss = 0.f;
        #pragma unroll
        for (int w = 0; w < 16; ++w) { es += pe[w]; ss += ps[w]; }
        out[(size_t)N_ROWS * DIM]     = 1.25f * (ss / (float)(N_ROWS * DIM));
        out[(size_t)N_ROWS * DIM + 1] = expf(-es);
    }
}

extern "C" void kernel_launch(void* const* d_in, const int* in_sizes, int n_in,
                              void* d_out, int out_size, void* d_ws, size_t ws_size,
                              hipStream_t stream) {
    const float* x   = (const float*)d_in[0];
    const float* emb = (const float*)d_in[1];
    float*  out    = (float*)d_out;
    float*  nh     = (float*)d_ws;
    int*    counts = (int*)((char*)d_ws + 4096);
    float*  ssePrt = (float*)((char*)d_ws + 8192);
    ushort* blob   = (ushort*)((char*)d_ws + 16384);

    vq_prep<<<16, 256, 0, stream>>>(emb, nh, counts, blob);
    vq_main<<<N_ROWS / MB, 256, 0, stream>>>(x, emb, blob, nh, out, counts, ssePrt);
    vq_final<<<1, 1024, 0, stream>>>(counts, ssePrt, out);
}